// Round 1
// 746.827 us; speedup vs baseline: 1.0651x; 1.0651x over previous
//
#include <hip/hip_runtime.h>
#include <hip/hip_bf16.h>
#include <math.h>

// CriticNetwork fused MFMA kernel (round 4).
// Round 4: B-fragments are loaded global->VGPR directly (each fragment is
// consumed by exactly one wave, so the old LDS staging + 2 barriers/chunk
// was pure overhead). Sur loop double-buffers s_a with 1 barrier/chunk and
// 1-deep register prefetch of state2. Judgement tail shares W_j1 loads
// across 4 rows. Numerics identical to round 3 (validated absmax ~1.2e-3).
//
// Algebra (validated round 1):
//  * inner MHA seq_len==1 -> softmax==1 -> Wcq/Wck dead.
//  * concat@W_out == cc @ Weff, Weff[(h*256+i)][o] = sum_j Wcv[i][j] W_out[h*256+j][o]
//  * score[b,k] = sur[b,k] . u[b],  u = own @ Mt2, Mt2[l][i] = sum_j Wk[i][j] Wq[l][j]
//  * v_att = (sum_k alpha_k sur_k) @ Wv

typedef __attribute__((ext_vector_type(8))) short bf16x8;
typedef __attribute__((ext_vector_type(4))) float f32x4;

#define KN     8
#define OBS0V  80
#define OBS1V  160
#define OBS2V  384
#define DD     256
#define MB     16   // batch rows per block

__device__ inline ushort f2bf(float x) {
    union { __hip_bfloat16 h; ushort u; } c;
    c.h = __float2bfloat16(x);
    return c.u;
}
__device__ inline float bf2f(ushort u) {
    union { ushort s[2]; float f; } c;
    c.s[0] = 0; c.s[1] = u;
    return c.f;
}
__device__ inline void pack_store8(void* dst, float4 a, float4 b) {
    union { ushort u[8]; uint4 q; } pk;
    pk.u[0]=f2bf(a.x); pk.u[1]=f2bf(a.y); pk.u[2]=f2bf(a.z); pk.u[3]=f2bf(a.w);
    pk.u[4]=f2bf(b.x); pk.u[5]=f2bf(b.y); pk.u[6]=f2bf(b.z); pk.u[7]=f2bf(b.w);
    *(uint4*)dst = pk.q;
}

// ---------------- prep kernels (fp32, tiny) ----------------
__global__ void precompute_M(const float* __restrict__ Wk,
                             const float* __restrict__ Wq,
                             float* __restrict__ Mt) {
    __shared__ float wq[DD];
    const int l = blockIdx.x, i = threadIdx.x;
    wq[i] = Wq[l * DD + i];
    __syncthreads();
    const float4* wk4 = (const float4*)(Wk + (size_t)i * DD);
    float acc = 0.f;
#pragma unroll 8
    for (int j = 0; j < DD / 4; ++j) {
        const float4 a = wk4[j];
        const float4 b = *(const float4*)&wq[j * 4];
        acc += a.x * b.x + a.y * b.y + a.z * b.z + a.w * b.w;
    }
    Mt[l * DD + i] = acc;
}

__global__ void precompute_Weff(const float* __restrict__ Wcv,
                                const float* __restrict__ Wout,
                                float* __restrict__ Weff) {
    const int bh = blockIdx.x;
    const int h = bh >> 8, i = bh & 255;
    const int o = threadIdx.x;
    const float* wrow = Wcv + (size_t)i * DD;
    float acc = 0.f;
#pragma unroll 4
    for (int j = 0; j < DD; ++j)
        acc += wrow[j] * Wout[(size_t)(h * DD + j) * 128 + o];
    Weff[(size_t)bh * 128 + o] = acc;
}

// Swizzle all weights into MFMA B-fragment order, bf16, zero-padded K.
__global__ void layout_all(const float* __restrict__ Wown, const float* __restrict__ Wenv,
                           const float* __restrict__ Wsur, const float* __restrict__ Mt2f,
                           const float* __restrict__ Wvf,  const float* __restrict__ Wefff,
                           ushort* __restrict__ pre) {
    const int idx8 = blockIdx.x * blockDim.x + threadIdx.x;
    if (idx8 >= 49152) return;
    const float* src; int Ksrc, N, NT, local;
    if (idx8 < 3072)       { src=Wown;  Ksrc=80;  N=256; NT=16; local=idx8;        }
    else if (idx8 < 8192)  { src=Wenv;  Ksrc=160; N=256; NT=16; local=idx8-3072;   }
    else if (idx8 < 20480) { src=Wsur;  Ksrc=384; N=256; NT=16; local=idx8-8192;   }
    else if (idx8 < 28672) { src=Mt2f;  Ksrc=256; N=256; NT=16; local=idx8-20480;  }
    else if (idx8 < 36864) { src=Wvf;   Ksrc=256; N=256; NT=16; local=idx8-28672;  }
    else                   { src=Wefff; Ksrc=768; N=128; NT=8;  local=idx8-36864;  }
    const int lane = local & 63;
    const int nt   = (local >> 6) & (NT - 1);
    const int kc   = local / (64 * NT);
    const int n    = nt * 16 + (lane & 15);
    const int k0   = kc * 32 + (lane >> 4) * 8;
    union { ushort u[8]; uint4 q; } pk;
#pragma unroll
    for (int j = 0; j < 8; ++j) {
        const int k = k0 + j;
        pk.u[j] = (k < Ksrc) ? f2bf(src[(size_t)k * N + n]) : (ushort)0;
    }
    *(uint4*)(pre + (size_t)idx8 * 8) = pk.q;
}

// ---------------- main fused kernel ----------------
// A from LDS, B fragments straight from global (L2-hot), no internal barriers.
template<int NCH, int NT, int NTW>
__device__ inline void gemm_reg(const char* sA, int strideA, const ushort* wpre,
                                f32x4* acc, int w, int lane) {
    const int lm = lane & 15, lq = lane >> 4;
#pragma unroll
    for (int n = 0; n < NTW; ++n) acc[n] = (f32x4){0.f, 0.f, 0.f, 0.f};
#pragma unroll 4
    for (int kc = 0; kc < NCH; ++kc) {
        const bf16x8 af = *(const bf16x8*)(sA + lm * strideA + kc * 64 + lq * 16);
#pragma unroll
        for (int n = 0; n < NTW; ++n) {
            const bf16x8 bfr = *(const bf16x8*)(wpre +
                ((size_t)(kc * NT + w * NTW + n) * 64 + lane) * 8);
            acc[n] = __builtin_amdgcn_mfma_f32_16x16x32_bf16(af, bfr, acc[n], 0, 0, 0);
        }
    }
}

__global__ __launch_bounds__(256, 2) void critic_mfma(
    const float* __restrict__ state0, const float* __restrict__ state1,
    const float* __restrict__ state2,
    const float* __restrict__ b_own, const float* __restrict__ b_env,
    const float* __restrict__ b_sur, const float* __restrict__ b_out,
    const float* __restrict__ W_j1, const float* __restrict__ b_j1,
    const float* __restrict__ W_j2, const float* __restrict__ b_j2,
    const ushort* __restrict__ pre_own, const ushort* __restrict__ pre_env,
    const ushort* __restrict__ pre_sur, const ushort* __restrict__ pre_mt2,
    const ushort* __restrict__ pre_wv,  const ushort* __restrict__ pre_weff,
    float* __restrict__ out) {

    __shared__ __align__(16) ushort s_cc[MB * 776];      // 24832 B
    __shared__ __align__(16) ushort s_att[MB * 264];     //  8448 B (aliased by s_hid)
    __shared__ __align__(16) char   s_a[2 * 10240];      // 20480 B dbuf (aliased by s_multi)
    __shared__ float s_spart[2 * 128];                   // [wn][row]
    __shared__ float s_alpha[128];
    __shared__ float s_mask[128];

    const int t = threadIdx.x;
    const int lane = t & 63;
    const int w = t >> 6;
    const int lm = lane & 15, lq = lane >> 4;
    const int bbase = blockIdx.x * MB;

    // ---- stage state0 -> s_a (16 rows x 80 f32 -> bf16, stride 240 B, pad->0) ----
    if (t < 240) {
        const int row = t / 15, s = t % 15;
        if (s < 10) {
            const float* gp = state0 + (size_t)(bbase + row) * OBS0V + s * 8;
            pack_store8(s_a + row * 240 + s * 16, *(const float4*)gp, *(const float4*)(gp + 4));
        } else {
            uint4 z; z.x = z.y = z.z = z.w = 0u;
            *(uint4*)(s_a + row * 240 + s * 16) = z;
        }
    }
    __syncthreads();

    // ---- own = relu(state0 @ W_own + b_own) -> s_cc[:,0:256] ----
    {
        f32x4 acc[4];
        gemm_reg<3, 16, 4>(s_a, 240, pre_own, acc, w, lane);
#pragma unroll
        for (int n = 0; n < 4; ++n) {
            const int gc = (w * 4 + n) * 16 + lm;
            const float bv = b_own[gc];
#pragma unroll
            for (int r = 0; r < 4; ++r)
                s_cc[(size_t)(lq * 4 + r) * 776 + gc] = f2bf(fmaxf(acc[n][r] + bv, 0.f));
        }
    }
    __syncthreads();

    // ---- stage state1 -> s_a (16 x 160, stride 336 B, K exact) ----
    {
        const int row = t / 20, s = t % 20;
        const float* gp = state1 + (size_t)(bbase + row) * OBS1V + s * 8;
        pack_store8(s_a + row * 336 + s * 16, *(const float4*)gp, *(const float4*)(gp + 4));
        if (t < 64) {
            const int slot = t + 256, row2 = slot / 20, s2 = slot % 20;
            const float* gp2 = state1 + (size_t)(bbase + row2) * OBS1V + s2 * 8;
            pack_store8(s_a + row2 * 336 + s2 * 16, *(const float4*)gp2, *(const float4*)(gp2 + 4));
        }
    }
    __syncthreads();

    // ---- env = relu(state1 @ W_env + b_env) -> s_cc[:,256:512] ----
    {
        f32x4 acc[4];
        gemm_reg<5, 16, 4>(s_a, 336, pre_env, acc, w, lane);
#pragma unroll
        for (int n = 0; n < 4; ++n) {
            const int gc = (w * 4 + n) * 16 + lm;
            const float bv = b_env[gc];
#pragma unroll
            for (int r = 0; r < 4; ++r)
                s_cc[(size_t)(lq * 4 + r) * 776 + 256 + gc] = f2bf(fmaxf(acc[n][r] + bv, 0.f));
        }
    }

    // ---- issue sur chunk-0 state2 loads early (latency hides under u gemm) ----
    const int wm = w & 1, wn = w >> 1;
    const float* s2b = state2 + (size_t)bbase * KN * OBS2V;
    const int row0 = t >> 2, q0 = t & 3;
    const float* gbase  = s2b + (size_t)row0 * OBS2V + q0 * 8;
    const float* gbase2 = gbase + (size_t)64 * OBS2V;
    float4 p_a0 = *(const float4*)gbase;
    float4 p_a1 = *(const float4*)(gbase + 4);
    float4 p_c0 = *(const float4*)gbase2;
    float4 p_c1 = *(const float4*)(gbase2 + 4);

    // ---- u = own @ Mt2 -> s_cc[:,512:768] (reads cols 0:256 only; disjoint) ----
    {
        f32x4 acc[4];
        gemm_reg<8, 16, 4>((const char*)s_cc, 1552, pre_mt2, acc, w, lane);
#pragma unroll
        for (int n = 0; n < 4; ++n) {
            const int gc = (w * 4 + n) * 16 + lm;
#pragma unroll
            for (int r = 0; r < 4; ++r)
                s_cc[(size_t)(lq * 4 + r) * 776 + 512 + gc] = f2bf(acc[n][r]);
        }
    }
    __syncthreads();   // env's s_a reads done -> safe to overwrite s_a

    // ---- sur GEMM: 128 (b,k)-rows x 384 -> 256, dbuf s_a, 1 barrier/chunk ----
    float ms0 = 0.f, ms1 = 0.f;
    ms0 += p_a0.x + p_a0.y + p_a0.z + p_a0.w + p_a1.x + p_a1.y + p_a1.z + p_a1.w;
    pack_store8(s_a + row0 * 80 + q0 * 16, p_a0, p_a1);
    ms1 += p_c0.x + p_c0.y + p_c0.z + p_c0.w + p_c1.x + p_c1.y + p_c1.z + p_c1.w;
    pack_store8(s_a + (64 + row0) * 80 + q0 * 16, p_c0, p_c1);
    __syncthreads();

    f32x4 sacc[4][8];
#pragma unroll
    for (int a = 0; a < 4; ++a)
#pragma unroll
        for (int b2 = 0; b2 < 8; ++b2) sacc[a][b2] = (f32x4){0.f, 0.f, 0.f, 0.f};

    for (int kc = 0; kc < 12; ++kc) {
        const char* bufc = s_a + (kc & 1) * 10240;
        char* bufn = s_a + ((kc + 1) & 1) * 10240;
        float4 na0, na1, nc0, nc1;
        if (kc < 11) {   // prefetch next chunk (regs); consumed after MFMAs
            const float* gp  = gbase  + (kc + 1) * 32;
            const float* gp2 = gbase2 + (kc + 1) * 32;
            na0 = *(const float4*)gp;  na1 = *(const float4*)(gp + 4);
            nc0 = *(const float4*)gp2; nc1 = *(const float4*)(gp2 + 4);
        }
        bf16x8 bfr[8];
#pragma unroll
        for (int n = 0; n < 8; ++n)
            bfr[n] = *(const bf16x8*)(pre_sur +
                ((size_t)(kc * 16 + wn * 8 + n) * 64 + lane) * 8);
#pragma unroll
        for (int mt = 0; mt < 4; ++mt) {
            const bf16x8 af = *(const bf16x8*)(bufc + ((wm * 4 + mt) * 16 + lm) * 80 + lq * 16);
#pragma unroll
            for (int n = 0; n < 8; ++n)
                sacc[mt][n] = __builtin_amdgcn_mfma_f32_16x16x32_bf16(af, bfr[n], sacc[mt][n], 0, 0, 0);
        }
        if (kc < 11) {
            ms0 += na0.x + na0.y + na0.z + na0.w + na1.x + na1.y + na1.z + na1.w;
            pack_store8(bufn + row0 * 80 + q0 * 16, na0, na1);
            ms1 += nc0.x + nc0.y + nc0.z + nc0.w + nc1.x + nc1.y + nc1.z + nc1.w;
            pack_store8(bufn + (64 + row0) * 80 + q0 * 16, nc0, nc1);
        }
        __syncthreads();
    }
    // mask sums -> s_mask
    {
        float p = ms0;
        p += __shfl_xor(p, 1); p += __shfl_xor(p, 2);
        if (q0 == 0) s_mask[row0] = p;
        float p2 = ms1;
        p2 += __shfl_xor(p2, 1); p2 += __shfl_xor(p2, 2);
        if (q0 == 0) s_mask[64 + row0] = p2;
    }
    // bias + relu on sur fragments
    {
        float bs[8];
#pragma unroll
        for (int n = 0; n < 8; ++n) bs[n] = b_sur[wn * 128 + n * 16 + lm];
#pragma unroll
        for (int mt = 0; mt < 4; ++mt)
#pragma unroll
            for (int n = 0; n < 8; ++n)
#pragma unroll
                for (int r = 0; r < 4; ++r)
                    sacc[mt][n][r] = fmaxf(sacc[mt][n][r] + bs[n], 0.f);
    }
    // score partials: one partial per column-half (wn) per row
#pragma unroll
    for (int mt = 0; mt < 4; ++mt) {
        const int tm = wm * 4 + mt;
        const int bb = 2 * tm + (lq >> 1);
        float u8[8];
#pragma unroll
        for (int n = 0; n < 8; ++n)
            u8[n] = bf2f(s_cc[(size_t)bb * 776 + 512 + wn * 128 + n * 16 + lm]);
#pragma unroll
        for (int r = 0; r < 4; ++r) {
            float p = 0.f;
#pragma unroll
            for (int n = 0; n < 8; ++n) p += sacc[mt][n][r] * u8[n];
            p += __shfl_xor(p, 1); p += __shfl_xor(p, 2);
            p += __shfl_xor(p, 4); p += __shfl_xor(p, 8);
            if (lm == 0) s_spart[wn * 128 + tm * 16 + lq * 4 + r] = p;
        }
    }
    __syncthreads();
    // softmax over k (16 threads, one per batch row)
    if (t < MB) {
        float sc[8]; float mx = -INFINITY;
#pragma unroll
        for (int k = 0; k < 8; ++k) {
            const int row = t * 8 + k;
            const float s = s_spart[row] + s_spart[128 + row];
            sc[k] = (s_mask[row] != 0.f) ? s * 0.0625f : -INFINITY;
            mx = fmaxf(mx, sc[k]);
        }
        float e[8]; float dn = 0.f;
#pragma unroll
        for (int k = 0; k < 8; ++k) {
            e[k] = (sc[k] == -INFINITY) ? 0.f : __expf(sc[k] - mx);
            dn += e[k];
        }
        const float inv = (dn > 0.f) ? 1.f / dn : 0.f;
#pragma unroll
        for (int k = 0; k < 8; ++k) s_alpha[t * 8 + k] = e[k] * inv;
    }
    __syncthreads();
    // s_att[b] = sum_k alpha*sur (bf16)
#pragma unroll
    for (int mt = 0; mt < 4; ++mt) {
        const int tm = wm * 4 + mt;
        float al[4];
#pragma unroll
        for (int r = 0; r < 4; ++r) al[r] = s_alpha[tm * 16 + lq * 4 + r];
#pragma unroll
        for (int n = 0; n < 8; ++n) {
            float p = sacc[mt][n][0] * al[0] + sacc[mt][n][1] * al[1]
                    + sacc[mt][n][2] * al[2] + sacc[mt][n][3] * al[3];
            p += __shfl_xor(p, 16);
            const int col = wn * 128 + n * 16 + lm;
            if (lq == 0)      s_att[(size_t)(2 * tm) * 264 + col] = f2bf(p);
            else if (lq == 2) s_att[(size_t)(2 * tm + 1) * 264 + col] = f2bf(p);
        }
    }
    __syncthreads();

    // ---- v_att = s_att @ Wv -> s_cc[:,512:768] (overwrites dead u) ----
    {
        f32x4 acc[4];
        gemm_reg<8, 16, 4>((const char*)s_att, 528, pre_wv, acc, w, lane);
#pragma unroll
        for (int n = 0; n < 4; ++n) {
            const int gc = (w * 4 + n) * 16 + lm;
#pragma unroll
            for (int r = 0; r < 4; ++r)
                s_cc[(size_t)(lq * 4 + r) * 776 + 512 + gc] = f2bf(acc[n][r]);
        }
    }
    __syncthreads();

    // ---- multi = cc @ Weff + b_out -> s_multi (f32, aliases s_a) ----
    float* s_multi = (float*)s_a;
    {
        f32x4 acc[2];
        gemm_reg<24, 8, 2>((const char*)s_cc, 1552, pre_weff, acc, w, lane);
#pragma unroll
        for (int n = 0; n < 2; ++n) {
            const int gc = (w * 2 + n) * 16 + lm;
            const float bv = b_out[gc];
#pragma unroll
            for (int r = 0; r < 4; ++r)
                s_multi[(lq * 4 + r) * 128 + gc] = acc[n][r] + bv;
        }
    }
    __syncthreads();

    // ---- judgement tail (fp32): share W_j1 loads across 4 rows ----
    float* s_hid = (float*)s_att;
    {
        const int h = t & 63, b0r = t >> 6;
        const float bj = b_j1[h];
        float acc0 = bj, acc1 = bj, acc2 = bj, acc3 = bj;
#pragma unroll 4
        for (int o4 = 0; o4 < 32; ++o4) {
            const float w0 = W_j1[(o4 * 4 + 0) * 64 + h];
            const float w1 = W_j1[(o4 * 4 + 1) * 64 + h];
            const float w2 = W_j1[(o4 * 4 + 2) * 64 + h];
            const float w3 = W_j1[(o4 * 4 + 3) * 64 + h];
            const float4 m0 = *(const float4*)&s_multi[(b0r     ) * 128 + o4 * 4];
            const float4 m1 = *(const float4*)&s_multi[(b0r +  4) * 128 + o4 * 4];
            const float4 m2 = *(const float4*)&s_multi[(b0r +  8) * 128 + o4 * 4];
            const float4 m3 = *(const float4*)&s_multi[(b0r + 12) * 128 + o4 * 4];
            acc0 += m0.x * w0 + m0.y * w1 + m0.z * w2 + m0.w * w3;
            acc1 += m1.x * w0 + m1.y * w1 + m1.z * w2 + m1.w * w3;
            acc2 += m2.x * w0 + m2.y * w1 + m2.z * w2 + m2.w * w3;
            acc3 += m3.x * w0 + m3.y * w1 + m3.z * w2 + m3.w * w3;
        }
        s_hid[(b0r     ) * 64 + h] = fmaxf(acc0, 0.f);
        s_hid[(b0r +  4) * 64 + h] = fmaxf(acc1, 0.f);
        s_hid[(b0r +  8) * 64 + h] = fmaxf(acc2, 0.f);
        s_hid[(b0r + 12) * 64 + h] = fmaxf(acc3, 0.f);
    }
    __syncthreads();
    if (t < 64) {
        const int b2 = t >> 2, pp = t & 3;
        float a2 = 0.f;
#pragma unroll
        for (int h = 0; h < 16; ++h)
            a2 += s_hid[b2 * 64 + pp * 16 + h] * W_j2[pp * 16 + h];
        a2 += __shfl_xor(a2, 1); a2 += __shfl_xor(a2, 2);
        if (pp == 0) out[bbase + b2] = a2 + b_j2[0];
    }
}

extern "C" void kernel_launch(void* const* d_in, const int* in_sizes, int n_in,
                              void* d_out, int out_size, void* d_ws, size_t ws_size,
                              hipStream_t stream) {
    (void)n_in; (void)out_size; (void)ws_size;
    const float* state0 = (const float*)d_in[0];
    const float* state1 = (const float*)d_in[1];
    const float* state2 = (const float*)d_in[2];
    const float* W_own  = (const float*)d_in[3];
    const float* b_own  = (const float*)d_in[4];
    const float* W_env  = (const float*)d_in[5];
    const float* b_env  = (const float*)d_in[6];
    const float* W_sur  = (const float*)d_in[7];
    const float* b_sur  = (const float*)d_in[8];
    const float* Wq     = (const float*)d_in[9];
    const float* Wk     = (const float*)d_in[10];
    const float* Wv     = (const float*)d_in[11];
    // d_in[12]=Wcq, d_in[13]=Wck: dead (seq_len==1 softmax == 1)
    const float* Wcv    = (const float*)d_in[14];
    const float* W_out  = (const float*)d_in[15];
    const float* b_out  = (const float*)d_in[16];
    const float* W_j1   = (const float*)d_in[17];
    const float* b_j1   = (const float*)d_in[18];
    const float* W_j2   = (const float*)d_in[19];
    const float* b_j2   = (const float*)d_in[20];
    float* out = (float*)d_out;

    float* Mt2f  = (float*)d_ws;
    float* Wefff = Mt2f + 65536;
    ushort* pre  = (ushort*)((char*)d_ws + 655360);
    ushort* pre_own  = pre;
    ushort* pre_env  = pre + 24576;
    ushort* pre_sur  = pre + 65536;
    ushort* pre_mt2  = pre + 163840;
    ushort* pre_wv   = pre + 229376;
    ushort* pre_weff = pre + 294912;

    const int B = in_sizes[0] / OBS0V;

    precompute_M<<<256, 256, 0, stream>>>(Wk, Wq, Mt2f);
    precompute_Weff<<<768, 128, 0, stream>>>(Wcv, W_out, Wefff);
    layout_all<<<192, 256, 0, stream>>>(W_own, W_env, W_sur, Mt2f, Wv, Wefff, pre);
    critic_mfma<<<B / MB, 256, 0, stream>>>(state0, state1, state2,
        b_own, b_env, b_sur, b_out, W_j1, b_j1, W_j2, b_j2,
        pre_own, pre_env, pre_sur, pre_mt2, pre_wv, pre_weff, out);
}